// Round 1
// baseline (3734.862 us; speedup 1.0000x reference)
//
#include <hip/hip_runtime.h>
#include <hip/hip_cooperative_groups.h>

namespace cg = cooperative_groups;

#define SEQn 33
#define Fn   20480
#define Hn   900
#define Bn   2
#define WVn  100
#define OBJn 35
#define RELn 82
#define G4n  3600   // 4*H
#define Mn   66     // SEQ*B

__device__ __forceinline__ float sigf(float v) { return 1.0f / (1.0f + expf(-v)); }
__device__ __forceinline__ float dot4(float4 a, float4 b) {
  return a.x*b.x + a.y*b.y + a.z*b.z + a.w*b.w;
}

typedef const __attribute__((address_space(1))) void GV;
typedef __attribute__((address_space(3))) void LV;

// ---------------- K1: G1[r][m] = b_ih1[r]+b_hh1[r] + sum_k x[m][k]*w_ih1[r][k]
// grid 225 (16 rows each), 256 threads. Per thread: 4 rows x 33 m accumulators,
// kp (t&31) owns one float4-slice of each 128-float K-chunk; reduce over kp at end.
__global__ __launch_bounds__(256) void k_gemm1(
    const float* __restrict__ x, const float* __restrict__ w1,
    const float* __restrict__ bi, const float* __restrict__ bh,
    float* __restrict__ G1)
{
  __shared__ float xs[2][Mn*128];
  const int tid = threadIdx.x;
  const int r0 = blockIdx.x * 16;
  const int kp = tid & 31;
  const int rg = tid >> 5;
  const int rowgroup = rg >> 1;   // 0..3
  const int mhalf = rg & 1;       // 0..1
  const int rbase = r0 + rowgroup * 4;
  const int mbase = mhalf * 33;

  float acc[4][33];
  #pragma unroll
  for (int a = 0; a < 4; ++a)
    #pragma unroll
    for (int b = 0; b < 33; ++b) acc[a][b] = 0.0f;

  // prologue: stage chunk 0 into buf 0 (async direct-to-LDS)
  for (int i = tid; i < Mn*32; i += 256) {
    int m = i >> 5, c4 = i & 31;
    __builtin_amdgcn_global_load_lds((GV*)(x + (size_t)m*Fn + c4*4),
                                     (LV*)&xs[0][i*4], 16, 0, 0);
  }

  for (int c = 0; c < Fn/128; ++c) {
    const int buf = c & 1;
    asm volatile("s_waitcnt vmcnt(0)" ::: "memory");
    __syncthreads();
    if (c + 1 < Fn/128) {
      const int k0n = (c+1) * 128;
      for (int i = tid; i < Mn*32; i += 256) {
        int m = i >> 5, c4 = i & 31;
        __builtin_amdgcn_global_load_lds((GV*)(x + (size_t)m*Fn + k0n + c4*4),
                                         (LV*)&xs[buf^1][i*4], 16, 0, 0);
      }
    }
    const int k0 = c * 128;
    float4 w[4];
    #pragma unroll
    for (int ri = 0; ri < 4; ++ri)
      w[ri] = *(const float4*)(w1 + (size_t)(rbase+ri)*Fn + k0 + kp*4);
    #pragma unroll
    for (int mi = 0; mi < 33; ++mi) {
      float4 xv = *(const float4*)&xs[buf][(mbase+mi)*128 + kp*4];
      #pragma unroll
      for (int ri = 0; ri < 4; ++ri)
        acc[ri][mi] += dot4(w[ri], xv);
    }
  }

  // reduce partial K-slices across the 32 kp lanes
  #pragma unroll
  for (int ri = 0; ri < 4; ++ri)
    #pragma unroll
    for (int mi = 0; mi < 33; ++mi) {
      float v = acc[ri][mi];
      v += __shfl_xor(v, 16, 64);
      v += __shfl_xor(v, 8, 64);
      v += __shfl_xor(v, 4, 64);
      v += __shfl_xor(v, 2, 64);
      v += __shfl_xor(v, 1, 64);
      acc[ri][mi] = v;
    }
  if (kp == 0) {
    #pragma unroll
    for (int ri = 0; ri < 4; ++ri) {
      const int r = rbase + ri;
      const float bsum = bi[r] + bh[r];
      #pragma unroll
      for (int mi = 0; mi < 33; ++mi)
        G1[(size_t)r*Mn + mbase + mi] = acc[ri][mi] + bsum;
    }
  }
}

// ---------------- K2 (cooperative): layer-1 recurrence + layer-2 fused recurrence + heads
// grid 225 blocks, each owns hidden indices j0..j0+3 with all 4 gates (c stays local).
__global__ __launch_bounds__(256) void k_rec(
    const float* __restrict__ G1, float* __restrict__ out1, float* __restrict__ h2buf,
    const float* __restrict__ whh1,
    const float* __restrict__ wih2, const float* __restrict__ whh2,
    const float* __restrict__ bih2, const float* __restrict__ bhh2,
    const float* __restrict__ wobj1, const float* __restrict__ bobj1,
    const float* __restrict__ wrel,  const float* __restrict__ brel,
    const float* __restrict__ wobj2, const float* __restrict__ bobj2,
    const float* __restrict__ embed, float* __restrict__ dout)
{
  cg::grid_group grid = cg::this_grid();
  __shared__ float xls[Bn][1024];   // phase A: h_prev ; phase B: [out1_t | wv | 0]
  __shared__ float h2ls[Bn][1024];
  __shared__ float gex[16][Bn];
  __shared__ float cls[Bn][4];
  __shared__ float wvls[Bn][WVn];
  __shared__ float red[4];
  __shared__ int   idxls[Bn];

  const int tid = threadIdx.x;
  const int blk = blockIdx.x;
  const int j0 = blk * 4;
  const int rowl = tid >> 4;        // 0..15 : gate g = rowl>>2, jj = rowl&3
  const int kp = tid & 15;          // k-slice: k = kp*4 + e*64
  const int gg_ = rowl >> 2;
  const int jj = rowl & 3;
  const int r = gg_ * Hn + j0 + jj;

  if (tid < 8) {
    int m = tid & 1, q = tid >> 1;
    h2buf[(size_t)m*Hn + j0 + q] = 0.0f;   // zero h2 buffer 0 (own chunk)
    cls[m][q] = 0.0f;                      // layer-1 c state
  }

  // -------- Phase A: layer-1 recurrence; w_hh1 rows held in registers --------
  float4 wA[16];
  #pragma unroll
  for (int e = 0; e < 16; ++e) {
    int k = kp*4 + e*64;
    if (k <= Hn-4) wA[e] = *(const float4*)(whh1 + (size_t)r*Hn + k);
    else           wA[e] = make_float4(0.f,0.f,0.f,0.f);
  }

  for (int t = 0; t < SEQn; ++t) {
    for (int i = tid; i < 512; i += 256) {
      int m = i >> 8, k = (i & 255) * 4;
      float4 v = make_float4(0.f,0.f,0.f,0.f);
      if (t > 0 && k <= Hn-4)
        v = *(const float4*)(out1 + (size_t)(t-1)*(Bn*Hn) + m*Hn + k);
      *(float4*)&xls[m][k] = v;
    }
    __syncthreads();
    float a0 = 0.f, a1 = 0.f;
    #pragma unroll
    for (int e = 0; e < 16; ++e) {
      int k = kp*4 + e*64;
      if (k <= Hn-4) {
        float4 w = wA[e];
        a0 += dot4(w, *(const float4*)&xls[0][k]);
        a1 += dot4(w, *(const float4*)&xls[1][k]);
      }
    }
    a0 += __shfl_xor(a0, 8, 64); a0 += __shfl_xor(a0, 4, 64);
    a0 += __shfl_xor(a0, 2, 64); a0 += __shfl_xor(a0, 1, 64);
    a1 += __shfl_xor(a1, 8, 64); a1 += __shfl_xor(a1, 4, 64);
    a1 += __shfl_xor(a1, 2, 64); a1 += __shfl_xor(a1, 1, 64);
    if (kp == 0) {
      gex[rowl][0] = a0 + G1[(size_t)r*Mn + t*Bn + 0];
      gex[rowl][1] = a1 + G1[(size_t)r*Mn + t*Bn + 1];
    }
    __syncthreads();
    if (tid < 8) {
      int m = tid & 1, q = tid >> 1;
      float gi = gex[q][m], gf = gex[4+q][m], gG = gex[8+q][m], go = gex[12+q][m];
      float cc = sigf(gf)*cls[m][q] + sigf(gi)*tanhf(gG);
      cls[m][q] = cc;
      out1[(size_t)t*(Bn*Hn) + m*Hn + j0 + q] = sigf(go)*tanhf(cc);
    }
    __threadfence();
    grid.sync();
  }

  // -------- Phase B: layer-2 recurrence (streamed per-step weights) + heads --------
  if (tid < 8) { int m = tid & 1, q = tid >> 1; cls[m][q] = 0.0f; }  // c2 state

  for (int t = 0; t < SEQn; ++t) {
    for (int i = tid; i < 512; i += 256) {
      int m = i >> 8, k = (i & 255) * 4;
      float4 xv = make_float4(0.f,0.f,0.f,0.f);
      if (k <= Hn-4)
        xv = *(const float4*)(out1 + (size_t)t*(Bn*Hn) + m*Hn + k);
      else if (t >= SEQn-2 && k >= Hn && k <= Hn+WVn-4) {
        xv.x = wvls[m][k-Hn];   xv.y = wvls[m][k-Hn+1];
        xv.z = wvls[m][k-Hn+2]; xv.w = wvls[m][k-Hn+3];
      }
      *(float4*)&xls[m][k] = xv;
      float4 hv = make_float4(0.f,0.f,0.f,0.f);
      if (k <= Hn-4)
        hv = *(const float4*)(h2buf + (size_t)(t&1)*(Bn*Hn) + m*Hn + k);
      *(float4*)&h2ls[m][k] = hv;
    }
    __syncthreads();
    const float* wI = wih2 + ((size_t)t*G4n + r) * 1000;
    const float* wH = whh2 + ((size_t)t*G4n + r) * Hn;
    const int kmx = (t >= SEQn-2) ? (Hn+WVn-4) : (Hn-4);
    float a0 = 0.f, a1 = 0.f;
    #pragma unroll
    for (int e = 0; e < 16; ++e) {
      int k = kp*4 + e*64;
      if (k <= kmx) {
        float4 w = *(const float4*)(wI + k);
        a0 += dot4(w, *(const float4*)&xls[0][k]);
        a1 += dot4(w, *(const float4*)&xls[1][k]);
      }
      if (k <= Hn-4) {
        float4 w = *(const float4*)(wH + k);
        a0 += dot4(w, *(const float4*)&h2ls[0][k]);
        a1 += dot4(w, *(const float4*)&h2ls[1][k]);
      }
    }
    a0 += __shfl_xor(a0, 8, 64); a0 += __shfl_xor(a0, 4, 64);
    a0 += __shfl_xor(a0, 2, 64); a0 += __shfl_xor(a0, 1, 64);
    a1 += __shfl_xor(a1, 8, 64); a1 += __shfl_xor(a1, 4, 64);
    a1 += __shfl_xor(a1, 2, 64); a1 += __shfl_xor(a1, 1, 64);
    if (kp == 0) {
      float bb = bih2[(size_t)t*G4n + r] + bhh2[(size_t)t*G4n + r];
      gex[rowl][0] = a0 + bb;
      gex[rowl][1] = a1 + bb;
    }
    __syncthreads();
    if (tid < 8) {
      int m = tid & 1, q = tid >> 1;
      float gi = gex[q][m], gf = gex[4+q][m], gG = gex[8+q][m], go = gex[12+q][m];
      float cc = sigf(gf)*cls[m][q] + sigf(gi)*tanhf(gG);
      cls[m][q] = cc;
      h2buf[(size_t)((t+1)&1)*(Bn*Hn) + m*Hn + j0 + q] = sigf(go)*tanhf(cc);
    }
    __threadfence();
    grid.sync();

    if (t >= SEQn-3) {
      const int nout = (t == SEQn-2) ? RELn : OBJn;
      const float* wh  = (t == SEQn-3) ? wobj1 : (t == SEQn-2) ? wrel : wobj2;
      const float* bhp = (t == SEQn-3) ? bobj1 : (t == SEQn-2) ? brel : bobj2;
      const int off = (t == SEQn-3) ? 0 : (t == SEQn-2) ? (Bn*OBJn) : (Bn*OBJn + Bn*RELn);
      const float* h2p = h2buf + (size_t)((t+1)&1)*(Bn*Hn);
      if (blk < nout*Bn) {
        const int o = blk >> 1, m = blk & 1;
        float p = 0.f;
        if (tid < 225) {
          float4 wv4 = *(const float4*)(wh + (size_t)o*Hn + tid*4);
          float4 hv4 = *(const float4*)(h2p + (size_t)m*Hn + tid*4);
          p = dot4(wv4, hv4);
        }
        p += __shfl_xor(p, 32, 64); p += __shfl_xor(p, 16, 64);
        p += __shfl_xor(p, 8, 64);  p += __shfl_xor(p, 4, 64);
        p += __shfl_xor(p, 2, 64);  p += __shfl_xor(p, 1, 64);
        if ((tid & 63) == 0) red[tid >> 6] = p;
        __syncthreads();
        if (tid == 0)
          dout[off + m*nout + o] = red[0] + red[1] + red[2] + red[3] + bhp[o];
      }
      __threadfence();
      grid.sync();
      if (t < SEQn-1) {
        // every block computes argmax + word vector redundantly (no extra sync)
        if (tid < Bn) {
          const float* lg = dout + off + tid*nout;
          int best = 0; float bv = lg[0];
          for (int o2 = 1; o2 < nout; ++o2) { float v = lg[o2]; if (v > bv) { bv = v; best = o2; } }
          idxls[tid] = best + ((t == SEQn-2) ? OBJn : 0);
        }
        __syncthreads();
        for (int i = tid; i < Bn*WVn; i += 256) {
          int m = i / WVn, v = i % WVn;
          wvls[m][v] = embed[(size_t)idxls[m]*WVn + v];
        }
        __syncthreads();
      }
    }
  }
}

extern "C" void kernel_launch(void* const* d_in, const int* in_sizes, int n_in,
                              void* d_out, int out_size, void* d_ws, size_t ws_size,
                              hipStream_t stream)
{
  (void)in_sizes; (void)n_in; (void)out_size; (void)ws_size;
  const float* x     = (const float*)d_in[0];
  const float* wih1  = (const float*)d_in[1];
  const float* whh1  = (const float*)d_in[2];
  const float* bih1  = (const float*)d_in[3];
  const float* bhh1  = (const float*)d_in[4];
  const float* wih2  = (const float*)d_in[5];
  const float* whh2  = (const float*)d_in[6];
  const float* bih2  = (const float*)d_in[7];
  const float* bhh2  = (const float*)d_in[8];
  const float* wobj1 = (const float*)d_in[9];
  const float* bobj1 = (const float*)d_in[10];
  const float* wrel  = (const float*)d_in[11];
  const float* brel  = (const float*)d_in[12];
  const float* wobj2 = (const float*)d_in[13];
  const float* bobj2 = (const float*)d_in[14];
  const float* embed = (const float*)d_in[15];
  float* dout = (float*)d_out;

  float* ws = (float*)d_ws;
  float* G1    = ws;                              // 3600*66
  float* out1  = G1 + (size_t)G4n*Mn;             // 33*2*900
  float* h2buf = out1 + (size_t)SEQn*Bn*Hn;       // 2*2*900

  hipLaunchKernelGGL(k_gemm1, dim3(225), dim3(256), 0, stream, x, wih1, bih1, bhh1, G1);

  void* args[16];
  args[0]  = (void*)&G1;    args[1]  = (void*)&out1;  args[2]  = (void*)&h2buf;
  args[3]  = (void*)&whh1;  args[4]  = (void*)&wih2;  args[5]  = (void*)&whh2;
  args[6]  = (void*)&bih2;  args[7]  = (void*)&bhh2;  args[8]  = (void*)&wobj1;
  args[9]  = (void*)&bobj1; args[10] = (void*)&wrel;  args[11] = (void*)&brel;
  args[12] = (void*)&wobj2; args[13] = (void*)&bobj2; args[14] = (void*)&embed;
  args[15] = (void*)&dout;
  hipLaunchCooperativeKernel((void*)k_rec, dim3(225), dim3(256), args, 0, stream);
}

// Round 4
// 2720.617 us; speedup vs baseline: 1.3728x; 1.3728x over previous
//
#include <hip/hip_runtime.h>
#include <hip/hip_cooperative_groups.h>

namespace cg = cooperative_groups;

#define SEQn 33
#define Fn   20480
#define Hn   900
#define Bn   2
#define WVn  100
#define OBJn 35
#define RELn 82
#define G4n  3600
#define Mn   66
#define NBLK 225
#define NITV 37

__device__ __forceinline__ float sigf(float v){ return 1.f/(1.f+expf(-v)); }
__device__ __forceinline__ float dot4(float4 a, float4 b){ return a.x*b.x+a.y*b.y+a.z*b.z+a.w*b.w; }
__device__ __forceinline__ float wred(float v){
  #pragma unroll
  for (int d = 32; d >= 1; d >>= 1) v += __shfl_xor(v, d, 64);
  return v;
}

typedef const __attribute__((address_space(1))) void GV;
typedef __attribute__((address_space(3))) void LV;

// ---------------- K1 (verbatim round-1, proven): G1[r][m] = b + sum_k x[m][k]*w_ih1[r][k]
__global__ __launch_bounds__(256) void k_gemm1(
    const float* __restrict__ x, const float* __restrict__ w1,
    const float* __restrict__ bi, const float* __restrict__ bh,
    float* __restrict__ G1)
{
  __shared__ float xs[2][Mn*128];
  const int tid = threadIdx.x;
  const int r0 = blockIdx.x * 16;
  const int kp = tid & 31;
  const int rg = tid >> 5;
  const int rowgroup = rg >> 1;
  const int mhalf = rg & 1;
  const int rbase = r0 + rowgroup * 4;
  const int mbase = mhalf * 33;

  float acc[4][33];
  #pragma unroll
  for (int a = 0; a < 4; ++a)
    #pragma unroll
    for (int b = 0; b < 33; ++b) acc[a][b] = 0.0f;

  for (int i = tid; i < Mn*32; i += 256) {
    int m = i >> 5, c4 = i & 31;
    __builtin_amdgcn_global_load_lds((GV*)(x + (size_t)m*Fn + c4*4),
                                     (LV*)&xs[0][i*4], 16, 0, 0);
  }

  for (int c = 0; c < Fn/128; ++c) {
    const int buf = c & 1;
    asm volatile("s_waitcnt vmcnt(0)" ::: "memory");
    __syncthreads();
    if (c + 1 < Fn/128) {
      const int k0n = (c+1) * 128;
      for (int i = tid; i < Mn*32; i += 256) {
        int m = i >> 5, c4 = i & 31;
        __builtin_amdgcn_global_load_lds((GV*)(x + (size_t)m*Fn + k0n + c4*4),
                                         (LV*)&xs[buf^1][i*4], 16, 0, 0);
      }
    }
    const int k0 = c * 128;
    float4 w[4];
    #pragma unroll
    for (int ri = 0; ri < 4; ++ri)
      w[ri] = *(const float4*)(w1 + (size_t)(rbase+ri)*Fn + k0 + kp*4);
    #pragma unroll
    for (int mi = 0; mi < 33; ++mi) {
      float4 xv = *(const float4*)&xs[buf][(mbase+mi)*128 + kp*4];
      #pragma unroll
      for (int ri = 0; ri < 4; ++ri)
        acc[ri][mi] += dot4(w[ri], xv);
    }
  }

  #pragma unroll
  for (int ri = 0; ri < 4; ++ri)
    #pragma unroll
    for (int mi = 0; mi < 33; ++mi) {
      float v = acc[ri][mi];
      v += __shfl_xor(v, 16, 64);
      v += __shfl_xor(v, 8, 64);
      v += __shfl_xor(v, 4, 64);
      v += __shfl_xor(v, 2, 64);
      v += __shfl_xor(v, 1, 64);
      acc[ri][mi] = v;
    }
  if (kp == 0) {
    #pragma unroll
    for (int ri = 0; ri < 4; ++ri) {
      const int r = rbase + ri;
      const float bsum = bi[r] + bh[r];
      #pragma unroll
      for (int mi = 0; mi < 33; ++mi)
        G1[(size_t)r*Mn + mbase + mi] = acc[ri][mi] + bsum;
    }
  }
}

// ---------------- K2 (cooperative, 225 blocks x 512 thr): interval i = L1 step i ∥ L2 step i-1.
// Block owns j0..j0+3 for both layers; 8 waves, wave w owns rows rho = 2w, 2w+1
// (rho = gate*4 + jj); 64 lanes split K.
__global__ __launch_bounds__(512) void k_rec(
    const float* __restrict__ G1, float* __restrict__ out1, float* __restrict__ h2buf,
    const float* __restrict__ whh1,
    const float* __restrict__ wih2, const float* __restrict__ whh2,
    const float* __restrict__ bih2, const float* __restrict__ bhh2,
    const float* __restrict__ wobj1, const float* __restrict__ bobj1,
    const float* __restrict__ wrel,  const float* __restrict__ brel,
    const float* __restrict__ wobj2, const float* __restrict__ bobj2,
    const float* __restrict__ embed, float* __restrict__ dout)
{
  cg::grid_group grid = cg::this_grid();
  __shared__ float xls[Bn][1024];   // L2 input [out1_s | wv | 0]
  __shared__ float hls[Bn][904];    // L1 h_{i-1}
  __shared__ float h2l[Bn][904];    // L2 h_{s-1}
  __shared__ float gexA[16][Bn], gexB[16][Bn];   // [rho=gate*4+jj][m]
  __shared__ float cA[4][Bn], cB[4][Bn];         // [jj][m]
  __shared__ float red[4];
  __shared__ int idxls[Bn];

  const int tid = threadIdx.x;
  const int blk = blockIdx.x;
  const int j0 = blk * 4;
  const int wv_ = tid >> 6;         // 0..7
  const int lane = tid & 63;

  if (tid < 8) {
    const int jj = tid >> 1, m = tid & 1;
    cA[jj][m] = 0.f; cB[jj][m] = 0.f;
    h2buf[(size_t)m*Hn + j0 + jj] = 0.f;   // buffer 0
  }

  // L1 recurrent rows for this wave's 2 rho's, in registers for the whole kernel
  float4 wAreg[2][4];
  #pragma unroll
  for (int ri = 0; ri < 2; ++ri) {
    const int rho = wv_*2 + ri;
    const int gate = rho >> 2, jj = rho & 3;
    const size_t row = (size_t)gate*Hn + j0 + jj;
    #pragma unroll
    for (int e = 0; e < 4; ++e) {
      const int k = lane*4 + e*256;
      wAreg[ri][e] = (k <= Hn-4) ? *(const float4*)(whh1 + row*Hn + k)
                                 : make_float4(0.f,0.f,0.f,0.f);
    }
  }

  for (int i = 0; i < NITV; ++i) {
    const bool hasA = (i <= 32);
    const int  s = (i >= 1 && i <= 31) ? (i-1) : (i == 33) ? 31 : (i == 35) ? 32 : -1;
    const bool hasB = (s >= 0);

    if (i == 33 || i == 35) {       // argmax feedback (redundant per block)
      if (tid < Bn) {
        const int nout = (i == 33) ? OBJn : RELn;
        const float* lg = dout + ((i == 33) ? 0 : Bn*OBJn) + tid*nout;
        int best = 0; float bv = lg[0];
        for (int o = 1; o < nout; ++o) { float v = lg[o]; if (v > bv) { bv = v; best = o; } }
        idxls[tid] = best + ((i == 35) ? OBJn : 0);
      }
      __syncthreads();
    }

    // ---- stage inputs for this interval
    if (hasA) {
      for (int q = tid; q < 450; q += 512) {
        const int m = q / 225, kk = q % 225;
        float4 v = make_float4(0.f,0.f,0.f,0.f);
        if (i > 0) v = *(const float4*)(out1 + ((size_t)(i-1)*Bn + m)*Hn + kk*4);
        *(float4*)&hls[m][kk*4] = v;
      }
    }
    if (hasB) {
      {
        const int q = tid;              // exactly 512 entries
        const int m = q >> 8, kk = q & 255;
        float4 v = make_float4(0.f,0.f,0.f,0.f);
        if (kk < 225) v = *(const float4*)(out1 + ((size_t)s*Bn + m)*Hn + kk*4);
        else if (kk < 250 && s >= SEQn-2)
          v = *(const float4*)(embed + (size_t)idxls[m]*WVn + (kk-225)*4);
        *(float4*)&xls[m][kk*4] = v;
      }
      for (int q = tid; q < 450; q += 512) {
        const int m = q / 225, kk = q % 225;
        *(float4*)&h2l[m][kk*4] =
          *(const float4*)(h2buf + ((size_t)(s&1)*Bn + m)*Hn + kk*4);
      }
    }
    __syncthreads();

    if (hasA) {
      #pragma unroll
      for (int ri = 0; ri < 2; ++ri) {
        const int rho = wv_*2 + ri;
        float a0 = 0.f, a1 = 0.f;
        #pragma unroll
        for (int e = 0; e < 4; ++e) {
          const int k = lane*4 + e*256;
          if (k <= Hn-4) {
            a0 += dot4(wAreg[ri][e], *(const float4*)&hls[0][k]);
            a1 += dot4(wAreg[ri][e], *(const float4*)&hls[1][k]);
          }
        }
        a0 = wred(a0); a1 = wred(a1);
        if (lane == 0) {
          const int gate = rho >> 2, jj = rho & 3;
          const size_t rA = (size_t)gate*Hn + j0 + jj;
          gexA[rho][0] = a0 + G1[rA*Mn + i*Bn + 0];
          gexA[rho][1] = a1 + G1[rA*Mn + i*Bn + 1];
        }
      }
    }

    if (hasB) {
      const int kmxI = (s >= SEQn-2) ? 996 : 896;   // skip wv-cols when wv==0
      #pragma unroll
      for (int ri = 0; ri < 2; ++ri) {
        const int rho = wv_*2 + ri;
        const int gate = rho >> 2, jj = rho & 3;
        const size_t ro = (size_t)s*G4n + (size_t)gate*Hn + j0 + jj;
        const float* wI = wih2 + ro*1000;
        const float* wH = whh2 + ro*Hn;
        float b0 = 0.f, b1 = 0.f;
        #pragma unroll
        for (int e = 0; e < 4; ++e) {
          const int k = lane*4 + e*256;
          if (k <= kmxI) {
            const float4 wi = *(const float4*)(wI + k);
            b0 += dot4(wi, *(const float4*)&xls[0][k]);
            b1 += dot4(wi, *(const float4*)&xls[1][k]);
          }
          if (k <= Hn-4) {
            const float4 wh = *(const float4*)(wH + k);
            b0 += dot4(wh, *(const float4*)&h2l[0][k]);
            b1 += dot4(wh, *(const float4*)&h2l[1][k]);
          }
        }
        b0 = wred(b0); b1 = wred(b1);
        if (lane == 0) {
          const float bb = bih2[ro] + bhh2[ro];
          gexB[rho][0] = b0 + bb;
          gexB[rho][1] = b1 + bb;
        }
      }
    }

    if (i == 32 || i == 34 || i == 36) {  // heads: obj1 / rel / obj2
      const int nout = (i == 34) ? RELn : OBJn;
      const float* wh  = (i == 32) ? wobj1 : (i == 34) ? wrel : wobj2;
      const float* bh_ = (i == 32) ? bobj1 : (i == 34) ? brel : bobj2;
      const int off = (i == 32) ? 0 : (i == 34) ? (Bn*OBJn) : (Bn*OBJn + Bn*RELn);
      const float* h2p = h2buf + (size_t)((i == 34) ? 0 : 1)*Bn*Hn;
      if (blk < nout*Bn) {
        const int o = blk >> 1, m = blk & 1;
        float p = 0.f;
        if (tid < 225)
          p = dot4(*(const float4*)(wh + (size_t)o*Hn + tid*4),
                   *(const float4*)(h2p + (size_t)m*Hn + tid*4));
        if (wv_ < 4) {
          const float pr = wred(p);
          if (lane == 0) red[wv_] = pr;
        }
        __syncthreads();
        if (tid == 0) dout[off + m*nout + o] = red[0]+red[1]+red[2]+red[3] + bh_[o];
      }
    }

    __syncthreads();
    if (tid < 8) {
      const int jj = tid >> 1, m = tid & 1;
      if (hasA) {
        const float cc = sigf(gexA[4+jj][m])*cA[jj][m]
                       + sigf(gexA[jj][m])*tanhf(gexA[8+jj][m]);
        cA[jj][m] = cc;
        out1[((size_t)i*Bn + m)*Hn + j0 + jj] = sigf(gexA[12+jj][m])*tanhf(cc);
      }
      if (hasB) {
        const float cc = sigf(gexB[4+jj][m])*cB[jj][m]
                       + sigf(gexB[jj][m])*tanhf(gexB[8+jj][m]);
        cB[jj][m] = cc;
        h2buf[((size_t)((s+1)&1)*Bn + m)*Hn + j0 + jj] = sigf(gexB[12+jj][m])*tanhf(cc);
      }
    }

    if (i < NITV-1) { __threadfence(); grid.sync(); }
  }
}

extern "C" void kernel_launch(void* const* d_in, const int* in_sizes, int n_in,
                              void* d_out, int out_size, void* d_ws, size_t ws_size,
                              hipStream_t stream)
{
  (void)in_sizes; (void)n_in; (void)out_size; (void)ws_size;
  const float* x     = (const float*)d_in[0];
  const float* wih1  = (const float*)d_in[1];
  const float* whh1  = (const float*)d_in[2];
  const float* bih1  = (const float*)d_in[3];
  const float* bhh1  = (const float*)d_in[4];
  const float* wih2  = (const float*)d_in[5];
  const float* whh2  = (const float*)d_in[6];
  const float* bih2  = (const float*)d_in[7];
  const float* bhh2  = (const float*)d_in[8];
  const float* wobj1 = (const float*)d_in[9];
  const float* bobj1 = (const float*)d_in[10];
  const float* wrel  = (const float*)d_in[11];
  const float* brel  = (const float*)d_in[12];
  const float* wobj2 = (const float*)d_in[13];
  const float* bobj2 = (const float*)d_in[14];
  const float* embed = (const float*)d_in[15];
  float* dout = (float*)d_out;

  float* ws = (float*)d_ws;
  float* G1    = ws;                              // 3600*66     (same footprint as round 1)
  float* out1  = G1 + (size_t)G4n*Mn;             // 33*2*900
  float* h2buf = out1 + (size_t)SEQn*Bn*Hn;       // 2*2*900

  hipLaunchKernelGGL(k_gemm1, dim3(225), dim3(256), 0, stream, x, wih1, bih1, bhh1, G1);

  void* args[16];
  args[0]  = (void*)&G1;    args[1]  = (void*)&out1;  args[2]  = (void*)&h2buf;
  args[3]  = (void*)&whh1;  args[4]  = (void*)&wih2;  args[5]  = (void*)&whh2;
  args[6]  = (void*)&bih2;  args[7]  = (void*)&bhh2;  args[8]  = (void*)&wobj1;
  args[9]  = (void*)&bobj1; args[10] = (void*)&wrel;  args[11] = (void*)&brel;
  args[12] = (void*)&wobj2; args[13] = (void*)&bobj2; args[14] = (void*)&embed;
  args[15] = (void*)&dout;
  hipLaunchCooperativeKernel((void*)k_rec, dim3(NBLK), dim3(512), args, 0, stream);
}

// Round 5
// 836.649 us; speedup vs baseline: 4.4641x; 3.2518x over previous
//
#include <hip/hip_runtime.h>

#define SEQn 33
#define Fn   20480
#define Hn   900
#define Bn   2
#define WVn  100
#define OBJn 35
#define RELn 82
#define G4n  3600
#define Mn   66
#define KSn  2
#define KSL  (Fn/KSn)     // 10240
#define RBn  225          // row-blocks in K1
#define RPB  16           // rows per K1 block
#define NBLK 225
#define NITV 37

__device__ __forceinline__ float sigf(float v){ return 1.f/(1.f+expf(-v)); }
__device__ __forceinline__ float dot4(float4 a, float4 b){ return a.x*b.x+a.y*b.y+a.z*b.z+a.w*b.w; }
__device__ __forceinline__ float wred(float v){
  #pragma unroll
  for (int d = 32; d >= 1; d >>= 1) v += __shfl_xor(v, d, 64);
  return v;
}
// coherent (agent-scope, cache-bypassing) scalar access for cross-block data
__device__ __forceinline__ float gload(const float* p){
  return __hip_atomic_load((const float*)p, __ATOMIC_RELAXED, __HIP_MEMORY_SCOPE_AGENT);
}
__device__ __forceinline__ void gstore(float* p, float v){
  __hip_atomic_store(p, v, __ATOMIC_RELAXED, __HIP_MEMORY_SCOPE_AGENT);
}

typedef const __attribute__((address_space(1))) void GV;
typedef __attribute__((address_space(3))) void LV;

// lightweight grid barrier: relaxed agent atomics only (no L2 writeback/invalidate).
// bar[0]=generation, bar[32]=arrival count (different 128B lines).
__device__ __forceinline__ void gbar(unsigned* bar){
  __syncthreads();   // compiler drains vmcnt before s_barrier -> all block stores at IC
  if (threadIdx.x == 0) {
    unsigned g = __hip_atomic_load(&bar[0], __ATOMIC_RELAXED, __HIP_MEMORY_SCOPE_AGENT);
    unsigned cnt = __hip_atomic_fetch_add(&bar[32], 1u, __ATOMIC_RELAXED, __HIP_MEMORY_SCOPE_AGENT);
    if (cnt == (unsigned)(NBLK-1)) {
      __hip_atomic_store(&bar[32], 0u, __ATOMIC_RELAXED, __HIP_MEMORY_SCOPE_AGENT);
      asm volatile("s_waitcnt vmcnt(0)" ::: "memory");   // reset visible before gen bump
      __hip_atomic_store(&bar[0], g+1u, __ATOMIC_RELAXED, __HIP_MEMORY_SCOPE_AGENT);
    } else {
      unsigned cur;
      do {
        __builtin_amdgcn_s_sleep(8);
        cur = __hip_atomic_load(&bar[0], __ATOMIC_RELAXED, __HIP_MEMORY_SCOPE_AGENT);
      } while (cur == g);
    }
  }
  __syncthreads();
}

// ---------------- K1: G1p[ks][r][m] = partial_k x[m][k]*w_ih1[r][k] (+biases at ks==0)
// 450 blocks (225 row-blocks x 2 K-slices), 256 thr, 16 rows/block, 4 rows/thread.
__global__ __launch_bounds__(256) void k_gemm1(
    const float* __restrict__ x, const float* __restrict__ w1,
    const float* __restrict__ bi, const float* __restrict__ bh,
    float* __restrict__ G1p, unsigned* __restrict__ bar)
{
  const int tid = threadIdx.x;
  if (blockIdx.x == 0 && tid == 0) {   // init barrier for k_rec (each replay)
    __hip_atomic_store(&bar[0], 0u, __ATOMIC_RELAXED, __HIP_MEMORY_SCOPE_AGENT);
    __hip_atomic_store(&bar[32], 0u, __ATOMIC_RELAXED, __HIP_MEMORY_SCOPE_AGENT);
  }
  __shared__ float xs[2][Mn*128];
  const int rb = blockIdx.x % RBn;
  const int ks = blockIdx.x / RBn;
  const int kp = tid & 31;
  const int rg = tid >> 5;        // 0..7
  const int rowgrp = rg >> 1;     // 0..3
  const int mbase = (rg & 1)*33;
  const int rbase = rb*RPB + rowgrp*4;
  const int kofs = ks*KSL;

  float acc[4][33];
  #pragma unroll
  for (int a = 0; a < 4; ++a)
    #pragma unroll
    for (int b = 0; b < 33; ++b) acc[a][b] = 0.f;

  for (int i = tid; i < Mn*32; i += 256) {
    int m = i >> 5, q = i & 31;
    __builtin_amdgcn_global_load_lds((GV*)(x + (size_t)m*Fn + kofs + q*4),
                                     (LV*)&xs[0][i*4], 16, 0, 0);
  }
  float4 wc[4];
  #pragma unroll
  for (int ri = 0; ri < 4; ++ri)
    wc[ri] = *(const float4*)(w1 + (size_t)(rbase+ri)*Fn + kofs + kp*4);

  const int NC = KSL/128;   // 80
  for (int c = 0; c < NC; ++c) {
    const int buf = c & 1;
    asm volatile("s_waitcnt vmcnt(0)" ::: "memory");
    __syncthreads();
    float4 wn[4];
    if (c+1 < NC) {
      const int k0n = kofs + (c+1)*128;
      for (int i = tid; i < Mn*32; i += 256) {
        int m = i >> 5, q = i & 31;
        __builtin_amdgcn_global_load_lds((GV*)(x + (size_t)m*Fn + k0n + q*4),
                                         (LV*)&xs[buf^1][i*4], 16, 0, 0);
      }
      #pragma unroll
      for (int ri = 0; ri < 4; ++ri)
        wn[ri] = *(const float4*)(w1 + (size_t)(rbase+ri)*Fn + k0n + kp*4);
    }
    #pragma unroll
    for (int mi = 0; mi < 33; ++mi) {
      float4 xv = *(const float4*)&xs[buf][(mbase+mi)*128 + kp*4];
      #pragma unroll
      for (int ri = 0; ri < 4; ++ri) acc[ri][mi] += dot4(wc[ri], xv);
    }
    if (c+1 < NC) { wc[0]=wn[0]; wc[1]=wn[1]; wc[2]=wn[2]; wc[3]=wn[3]; }
  }

  #pragma unroll
  for (int ri = 0; ri < 4; ++ri)
    #pragma unroll
    for (int mi = 0; mi < 33; ++mi) {
      float v = acc[ri][mi];
      v += __shfl_xor(v, 16, 64);
      v += __shfl_xor(v, 8, 64);
      v += __shfl_xor(v, 4, 64);
      v += __shfl_xor(v, 2, 64);
      v += __shfl_xor(v, 1, 64);
      acc[ri][mi] = v;
    }
  if (kp == 0) {
    #pragma unroll
    for (int ri = 0; ri < 4; ++ri) {
      const int r = rbase + ri;
      const float bsum = (ks == 0) ? (bi[r] + bh[r]) : 0.f;
      for (int mi = 0; mi < 33; ++mi)
        G1p[((size_t)ks*G4n + r)*Mn + mbase + mi] = acc[ri][mi] + bsum;
    }
  }
}

// ---------------- K2 (cooperative, 225 x 512): interval i = L1 step i ∥ L2 step i-1.
// All cross-block data via relaxed agent atomics; custom barrier between intervals.
__global__ __launch_bounds__(512) void k_rec(
    const float* __restrict__ G1p, float* __restrict__ out1, float* __restrict__ h2buf,
    const float* __restrict__ whh1,
    const float* __restrict__ wih2, const float* __restrict__ whh2,
    const float* __restrict__ bih2, const float* __restrict__ bhh2,
    const float* __restrict__ wobj1, const float* __restrict__ bobj1,
    const float* __restrict__ wrel,  const float* __restrict__ brel,
    const float* __restrict__ wobj2, const float* __restrict__ bobj2,
    const float* __restrict__ embed, float* __restrict__ dout,
    unsigned* __restrict__ bar)
{
  __shared__ float hls[Bn][904];    // out1[src] (shared by L1-dot and L2-dot)
  __shared__ float h2l[Bn][904];    // L2 h_{s-1}
  __shared__ float wvls[Bn][104];   // word vector
  __shared__ float gexA[16][Bn], gexB[16][Bn];
  __shared__ float cA[4][Bn], cB[4][Bn];
  __shared__ float red[4];
  __shared__ int idxls[Bn];

  const int tid = threadIdx.x;
  const int blk = blockIdx.x;
  const int j0 = blk * 4;
  const int wv_ = tid >> 6;
  const int lane = tid & 63;

  if (tid < 8) {
    const int jj = tid >> 1, m = tid & 1;
    cA[jj][m] = 0.f; cB[jj][m] = 0.f;
    gstore(h2buf + (size_t)m*Hn + j0 + jj, 0.f);   // buffer 0
  }

  float4 wAreg[2][4];
  #pragma unroll
  for (int ri = 0; ri < 2; ++ri) {
    const int rho = wv_*2 + ri;
    const int gate = rho >> 2, jj = rho & 3;
    const size_t row = (size_t)gate*Hn + j0 + jj;
    #pragma unroll
    for (int e = 0; e < 4; ++e) {
      const int k = lane*4 + e*256;
      wAreg[ri][e] = (k <= Hn-4) ? *(const float4*)(whh1 + row*Hn + k)
                                 : make_float4(0.f,0.f,0.f,0.f);
    }
  }

  for (int i = 0; i < NITV; ++i) {
    const bool hasA = (i <= 32);
    const int  s = (i >= 1 && i <= 31) ? (i-1) : (i == 33) ? 31 : (i == 35) ? 32 : -1;
    const bool hasB = (s >= 0);

    if (i == 33 || i == 35) {       // wave-parallel argmax + word-vector fetch
      if (wv_ < 2) {
        const int m = wv_;
        const int nout = (i == 33) ? OBJn : RELn;
        const int off = (i == 33) ? 0 : Bn*OBJn;
        float v = -1e30f; int idx = 0;
        for (int o = lane; o < nout; o += 64) {
          float t = gload(dout + off + m*nout + o);
          if (t > v) { v = t; idx = o; }
        }
        #pragma unroll
        for (int d = 32; d >= 1; d >>= 1) {
          float ov = __shfl_xor(v, d, 64);
          int   oi = __shfl_xor(idx, d, 64);
          if (ov > v || (ov == v && oi < idx)) { v = ov; idx = oi; }
        }
        if (lane == 0) idxls[m] = idx + ((i == 35) ? OBJn : 0);
      }
      __syncthreads();
      for (int q = tid; q < Bn*104; q += 512) {
        const int m = q / 104, v4 = q % 104;
        wvls[m][v4] = (v4 < WVn) ? embed[(size_t)idxls[m]*WVn + v4] : 0.f;
      }
      __syncthreads();
    }

    // ---- stage h-state (coherent scalar loads)
    const bool stageH = hasA || (i == 35);
    const int  srcA = (i == 35) ? 32 : i-1;
    if (stageH) {
      for (int q = tid; q < 1808; q += 512) {
        const int m = q / 904, kk = q % 904;
        hls[m][kk] = (i > 0 && kk < 900)
          ? gload(out1 + ((size_t)srcA*Bn + m)*Hn + kk) : 0.f;
      }
    }
    if (hasB) {
      for (int q = tid; q < 1808; q += 512) {
        const int m = q / 904, kk = q % 904;
        h2l[m][kk] = (kk < 900)
          ? gload(h2buf + ((size_t)(s&1)*Bn + m)*Hn + kk) : 0.f;
      }
    }
    __syncthreads();

    if (hasA) {
      #pragma unroll
      for (int ri = 0; ri < 2; ++ri) {
        const int rho = wv_*2 + ri;
        float a0 = 0.f, a1 = 0.f;
        #pragma unroll
        for (int e = 0; e < 4; ++e) {
          const int k = lane*4 + e*256;
          if (k <= Hn-4) {
            a0 += dot4(wAreg[ri][e], *(const float4*)&hls[0][k]);
            a1 += dot4(wAreg[ri][e], *(const float4*)&hls[1][k]);
          }
        }
        a0 = wred(a0); a1 = wred(a1);
        if (lane == 0) {
          const int gate = rho >> 2, jj = rho & 3;
          const size_t rA = (size_t)gate*Hn + j0 + jj;
          float g0 = 0.f, g1 = 0.f;
          #pragma unroll
          for (int kq = 0; kq < KSn; ++kq) {
            const float* gp = G1p + ((size_t)kq*G4n + rA)*Mn + i*Bn;
            g0 += gp[0]; g1 += gp[1];
          }
          gexA[rho][0] = a0 + g0;
          gexA[rho][1] = a1 + g1;
        }
      }
    }

    if (hasB) {
      #pragma unroll
      for (int ri = 0; ri < 2; ++ri) {
        const int rho = wv_*2 + ri;
        const int gate = rho >> 2, jj = rho & 3;
        const size_t ro = (size_t)s*G4n + (size_t)gate*Hn + j0 + jj;
        const float* wI = wih2 + ro*1000;
        const float* wH = whh2 + ro*Hn;
        float b0 = 0.f, b1 = 0.f;
        #pragma unroll
        for (int e = 0; e < 4; ++e) {
          const int k = lane*4 + e*256;
          if (k <= 896) {
            const float4 wi = *(const float4*)(wI + k);
            b0 += dot4(wi, *(const float4*)&hls[0][k]);
            b1 += dot4(wi, *(const float4*)&hls[1][k]);
            const float4 wh = *(const float4*)(wH + k);
            b0 += dot4(wh, *(const float4*)&h2l[0][k]);
            b1 += dot4(wh, *(const float4*)&h2l[1][k]);
          } else if (k >= 900 && k <= 996 && s >= SEQn-2) {
            const float4 wi = *(const float4*)(wI + k);
            b0 += dot4(wi, *(const float4*)&wvls[0][k-900]);
            b1 += dot4(wi, *(const float4*)&wvls[1][k-900]);
          }
        }
        b0 = wred(b0); b1 = wred(b1);
        if (lane == 0) {
          const float bb = bih2[ro] + bhh2[ro];
          gexB[rho][0] = b0 + bb;
          gexB[rho][1] = b1 + bb;
        }
      }
    }

    if (i == 32 || i == 34 || i == 36) {  // heads: obj1 / rel / obj2
      const int nout = (i == 34) ? RELn : OBJn;
      const float* wh  = (i == 32) ? wobj1 : (i == 34) ? wrel : wobj2;
      const float* bh_ = (i == 32) ? bobj1 : (i == 34) ? brel : bobj2;
      const int off = (i == 32) ? 0 : (i == 34) ? (Bn*OBJn) : (Bn*OBJn + Bn*RELn);
      const int hb = (i == 34) ? 0 : 1;
      if (blk < nout*Bn) {
        const int o = blk >> 1, m = blk & 1;
        float p = 0.f;
        if (tid < 225) {
          const float4 wv4 = *(const float4*)(wh + (size_t)o*Hn + tid*4);
          float* hp = h2buf + ((size_t)hb*Bn + m)*Hn + tid*4;
          p = wv4.x*gload(hp+0) + wv4.y*gload(hp+1)
            + wv4.z*gload(hp+2) + wv4.w*gload(hp+3);
        }
        if (wv_ < 4) {
          const float pr = wred(p);
          if (lane == 0) red[wv_] = pr;
        }
        __syncthreads();
        if (tid == 0)
          gstore(&dout[off + m*nout + o], red[0]+red[1]+red[2]+red[3] + bh_[o]);
      }
    }

    __syncthreads();
    if (tid < 8) {
      const int jj = tid >> 1, m = tid & 1;
      if (hasA) {
        const float cc = sigf(gexA[4+jj][m])*cA[jj][m]
                       + sigf(gexA[jj][m])*tanhf(gexA[8+jj][m]);
        cA[jj][m] = cc;
        gstore(out1 + ((size_t)i*Bn + m)*Hn + j0 + jj, sigf(gexA[12+jj][m])*tanhf(cc));
      }
      if (hasB) {
        const float cc = sigf(gexB[4+jj][m])*cB[jj][m]
                       + sigf(gexB[jj][m])*tanhf(gexB[8+jj][m]);
        cB[jj][m] = cc;
        gstore(h2buf + ((size_t)((s+1)&1)*Bn + m)*Hn + j0 + jj,
               sigf(gexB[12+jj][m])*tanhf(cc));
      }
    }

    if (i < NITV-1) gbar(bar);
  }
}

extern "C" void kernel_launch(void* const* d_in, const int* in_sizes, int n_in,
                              void* d_out, int out_size, void* d_ws, size_t ws_size,
                              hipStream_t stream)
{
  (void)in_sizes; (void)n_in; (void)out_size; (void)ws_size;
  const float* x     = (const float*)d_in[0];
  const float* wih1  = (const float*)d_in[1];
  const float* whh1  = (const float*)d_in[2];
  const float* bih1  = (const float*)d_in[3];
  const float* bhh1  = (const float*)d_in[4];
  const float* wih2  = (const float*)d_in[5];
  const float* whh2  = (const float*)d_in[6];
  const float* bih2  = (const float*)d_in[7];
  const float* bhh2  = (const float*)d_in[8];
  const float* wobj1 = (const float*)d_in[9];
  const float* bobj1 = (const float*)d_in[10];
  const float* wrel  = (const float*)d_in[11];
  const float* brel  = (const float*)d_in[12];
  const float* wobj2 = (const float*)d_in[13];
  const float* bobj2 = (const float*)d_in[14];
  const float* embed = (const float*)d_in[15];
  float* dout = (float*)d_out;

  float* ws = (float*)d_ws;
  float* G1p   = ws;                                  // 2*3600*66
  float* out1  = G1p + (size_t)KSn*G4n*Mn;            // 33*2*900
  float* h2buf = out1 + (size_t)SEQn*Bn*Hn;           // 2*2*900
  unsigned* bar = (unsigned*)(h2buf + (size_t)2*Bn*Hn);

  hipLaunchKernelGGL(k_gemm1, dim3(RBn*KSn), dim3(256), 0, stream,
                     x, wih1, bih1, bhh1, G1p, bar);

  void* args[17];
  args[0]  = (void*)&G1p;   args[1]  = (void*)&out1;  args[2]  = (void*)&h2buf;
  args[3]  = (void*)&whh1;  args[4]  = (void*)&wih2;  args[5]  = (void*)&whh2;
  args[6]  = (void*)&bih2;  args[7]  = (void*)&bhh2;  args[8]  = (void*)&wobj1;
  args[9]  = (void*)&bobj1; args[10] = (void*)&wrel;  args[11] = (void*)&brel;
  args[12] = (void*)&wobj2; args[13] = (void*)&bobj2; args[14] = (void*)&embed;
  args[15] = (void*)&dout;  args[16] = (void*)&bar;
  hipLaunchCooperativeKernel((void*)k_rec, dim3(NBLK), dim3(512), args, 0, stream);
}